// Round 7
// baseline (98.303 us; speedup 1.0000x reference)
//
#include <hip/hip_runtime.h>
#include <hip/hip_fp16.h>

// Problem constants (reference: B=4, N=512, F_IN=F_OUT=128)
constexpr int B_   = 4;
constexpr int N_   = 512;
constexpr int F    = 128;
constexpr int RB   = 8;     // rows per producer/consumer unit
constexpr int LSTW = 520;   // neighbor-list stride (512 + pad)

// ---------------------------------------------------------------------------
// Fused producer-consumer kernel. 512 blocks x 512 threads = EXACTLY the
// 2-blocks/CU x 256-CU capacity (launch_bounds(512,4) caps VGPR<=128,
// LDS 53.3KB <= 80KB/block) -> all blocks co-resident -> spin is deadlock-free
// (producers never wait on consumers).
//
// even blocks (idx = bid>>1): producer for rows idx*8..idx*8+7
//   - ballot-compact 8 adj rows directly to lstG/cntG (sentinel pads)
//   - triple GEMM f32: xi = x@Wi+b (f32), xj = x@Wj (fp16), xu = x@Wupd[0:F]
//   - threadfence + agent-release atomicAdd(c1[batch])
// odd blocks: consumer for rows idx*8..idx*8+7
//   - relaxed-spin until c1[batch]==64, one agent-acquire load (cache inv)
//   - per-wave gather over fp16 xj, update GEMM, out = relu(xu+agg@W2+b)
// ---------------------------------------------------------------------------
__global__ __launch_bounds__(512, 4) void k_all(
    const float* __restrict__ x,
    const float* __restrict__ adj,
    const float* __restrict__ Wmsg,
    const float* __restrict__ bmsg,
    const float* __restrict__ Wupd,
    const float* __restrict__ bupd,
    float*  __restrict__ xi,
    __half* __restrict__ xjH,
    float*  __restrict__ xu,
    int*    __restrict__ lstG,
    int*    __restrict__ cntG,
    int*    __restrict__ c1,
    float*  __restrict__ out)
{
    __shared__ union {
        struct { __align__(16) float xs[RB][F]; float ps[4][3 * RB][F]; } p; // 53.2 KB
        struct { __align__(16) float agg[RB][F]; } g;                        //  4 KB
    } sm;

    const int t    = threadIdx.x;
    const int lane = t & 63;
    const int w    = t >> 6;              // wave 0..7
    const int q    = t >> 7;              // quarter 0..3
    const int o    = t & 127;             // output column
    const int role = blockIdx.x & 1;
    const int idx  = blockIdx.x >> 1;     // 0..255
    const int r0   = idx * RB;            // global row base
    const int b    = r0 >> 9;             // batch

    if (role == 0) {
        // ================= PRODUCER =================
        const int PADJ = (B_ * N_ + b) - b * N_;   // per-batch sentinel row

        // per-batch sentinel xj row: relu(xi - 60000) == 0
        if ((idx & 63) == 0 && t < F)
            xjH[(size_t)(B_ * N_ + b) * F + t] = __float2half(-60000.f);

        // x rows -> LDS
        for (int ix = t; ix < RB * F; ix += 512)
            sm.p.xs[ix >> 7][ix & 127] = x[(size_t)r0 * F + ix];

        // ballot compaction: wave w owns row w, lists straight to global
        {
            const float* arow = adj + (size_t)(r0 + w) * N_;
            int* lrow = lstG + (size_t)(r0 + w) * LSTW;
            int base = 0;
            #pragma unroll
            for (int s = 0; s < 8; ++s) {
                const float a = arow[s * 64 + lane];
                const unsigned long long m = __ballot(a != 0.f);
                const int off = __popcll(m & ((1ull << lane) - 1ull));
                if (a != 0.f) lrow[base + off] = s * 64 + lane;
                base += __popcll(m);
            }
            const int np = (base + 7) & ~7;
            if (lane < np - base) lrow[base + lane] = PADJ;   // sentinel pads
            if (lane == 0) cntG[r0 + w] = np;
        }
        __syncthreads();

        // triple GEMM, K-quarter q (32 k's), 8 rows, 3 outputs
        float ai[RB] = {0,0,0,0,0,0,0,0};
        float aj[RB] = {0,0,0,0,0,0,0,0};
        float au[RB] = {0,0,0,0,0,0,0,0};
        const int kb = q * 32;
        #pragma unroll
        for (int k = 0; k < 32; k += 4) {
            float4 xv[RB];
            #pragma unroll
            for (int r = 0; r < RB; ++r)
                xv[r] = *reinterpret_cast<const float4*>(&sm.p.xs[r][kb + k]);
            #pragma unroll
            for (int u = 0; u < 4; ++u) {
                const int kk = kb + k + u;
                const float wi = Wmsg[(size_t)kk * F + o];
                const float wj = Wmsg[(size_t)(F + kk) * F + o];
                const float wu = Wupd[(size_t)kk * F + o];
                #pragma unroll
                for (int r = 0; r < RB; ++r) {
                    const float xk = reinterpret_cast<const float*>(&xv[r])[u];
                    ai[r] = fmaf(xk, wi, ai[r]);
                    aj[r] = fmaf(xk, wj, aj[r]);
                    au[r] = fmaf(xk, wu, au[r]);
                }
            }
        }
        #pragma unroll
        for (int r = 0; r < RB; ++r) {
            sm.p.ps[q][r][o]          = ai[r];
            sm.p.ps[q][RB + r][o]     = aj[r];
            sm.p.ps[q][2 * RB + r][o] = au[r];
        }
        __syncthreads();

        // combine: q-group handles 6 of the 24 output rows
        const float bm = bmsg[o];
        #pragma unroll
        for (int i = 0; i < 6; ++i) {
            const int v = q * 6 + i;
            const int r = v & (RB - 1);
            const float s = sm.p.ps[0][v][o] + sm.p.ps[1][v][o]
                          + sm.p.ps[2][v][o] + sm.p.ps[3][v][o];
            if (v < RB)            xi[(size_t)(r0 + r) * F + o] = s + bm;
            else if (v < 2 * RB)   xjH[(size_t)(r0 + r) * F + o] = __float2half(s);
            else                   xu[(size_t)(r0 + r) * F + o] = s;
        }
        __syncthreads();                       // all stores issued & drained
        __threadfence();                       // agent fence: L2 writeback
        if (t == 0)
            __hip_atomic_fetch_add(&c1[b], 1, __ATOMIC_RELEASE,
                                   __HIP_MEMORY_SCOPE_AGENT);
    } else {
        // ================= CONSUMER =================
        if (t == 0) {
            while (__hip_atomic_load(&c1[b], __ATOMIC_RELAXED,
                                     __HIP_MEMORY_SCOPE_AGENT) < 64)
                __builtin_amdgcn_s_sleep(2);
            // one acquire: invalidate this CU's L1 + XCD L2 (stale lines)
            (void)__hip_atomic_load(&c1[b], __ATOMIC_ACQUIRE,
                                    __HIP_MEMORY_SCOPE_AGENT);
        }
        __syncthreads();

        // gather: wave w owns row r0+w (8-deep unroll, index prefetch)
        {
            const __half* xjb = xjH + (size_t)b * N_ * F;
            const float2 xir2 = *reinterpret_cast<const float2*>(
                &xi[(size_t)(r0 + w) * F + 2 * lane]);
            const int np = cntG[r0 + w];
            const int* lrow = lstG + (size_t)(r0 + w) * LSTW;
            float2 acc = {0.f, 0.f};

            if (np > 0) {
                int4 a = *reinterpret_cast<const int4*>(&lrow[0]);
                int4 c = *reinterpret_cast<const int4*>(&lrow[4]);
                for (int k = 0; k < np; k += 8) {
                    const int4 an = *reinterpret_cast<const int4*>(&lrow[k + 8]);
                    const int4 cn = *reinterpret_cast<const int4*>(&lrow[k + 12]);
                    const float2 v0 = __half22float2(*reinterpret_cast<const __half2*>(&xjb[(size_t)a.x * F + 2 * lane]));
                    const float2 v1 = __half22float2(*reinterpret_cast<const __half2*>(&xjb[(size_t)a.y * F + 2 * lane]));
                    const float2 v2 = __half22float2(*reinterpret_cast<const __half2*>(&xjb[(size_t)a.z * F + 2 * lane]));
                    const float2 v3 = __half22float2(*reinterpret_cast<const __half2*>(&xjb[(size_t)a.w * F + 2 * lane]));
                    const float2 v4 = __half22float2(*reinterpret_cast<const __half2*>(&xjb[(size_t)c.x * F + 2 * lane]));
                    const float2 v5 = __half22float2(*reinterpret_cast<const __half2*>(&xjb[(size_t)c.y * F + 2 * lane]));
                    const float2 v6 = __half22float2(*reinterpret_cast<const __half2*>(&xjb[(size_t)c.z * F + 2 * lane]));
                    const float2 v7 = __half22float2(*reinterpret_cast<const __half2*>(&xjb[(size_t)c.w * F + 2 * lane]));
                    acc.x += fmaxf(xir2.x + v0.x, 0.f);  acc.y += fmaxf(xir2.y + v0.y, 0.f);
                    acc.x += fmaxf(xir2.x + v1.x, 0.f);  acc.y += fmaxf(xir2.y + v1.y, 0.f);
                    acc.x += fmaxf(xir2.x + v2.x, 0.f);  acc.y += fmaxf(xir2.y + v2.y, 0.f);
                    acc.x += fmaxf(xir2.x + v3.x, 0.f);  acc.y += fmaxf(xir2.y + v3.y, 0.f);
                    acc.x += fmaxf(xir2.x + v4.x, 0.f);  acc.y += fmaxf(xir2.y + v4.y, 0.f);
                    acc.x += fmaxf(xir2.x + v5.x, 0.f);  acc.y += fmaxf(xir2.y + v5.y, 0.f);
                    acc.x += fmaxf(xir2.x + v6.x, 0.f);  acc.y += fmaxf(xir2.y + v6.y, 0.f);
                    acc.x += fmaxf(xir2.x + v7.x, 0.f);  acc.y += fmaxf(xir2.y + v7.y, 0.f);
                    a = an; c = cn;
                }
            }
            *reinterpret_cast<float2*>(&sm.g.agg[w][2 * lane]) = acc;
        }
        __syncthreads();

        // update GEMM: rows 2q, 2q+1, full K=128
        float res0 = 0.f, res1 = 0.f;
        const int rA = 2 * q, rB2 = 2 * q + 1;
        #pragma unroll
        for (int k = 0; k < F; k += 4) {
            const float4 a0 = *reinterpret_cast<const float4*>(&sm.g.agg[rA][k]);
            const float4 a1 = *reinterpret_cast<const float4*>(&sm.g.agg[rB2][k]);
            #pragma unroll
            for (int u = 0; u < 4; ++u) {
                const float wv = Wupd[(size_t)(F + k + u) * F + o];
                res0 = fmaf(reinterpret_cast<const float*>(&a0)[u], wv, res0);
                res1 = fmaf(reinterpret_cast<const float*>(&a1)[u], wv, res1);
            }
        }
        const float bu = bupd[o];
        out[(size_t)(r0 + rA) * F + o] =
            fmaxf(res0 + xu[(size_t)(r0 + rA) * F + o] + bu, 0.f);
        out[(size_t)(r0 + rB2) * F + o] =
            fmaxf(res1 + xu[(size_t)(r0 + rB2) * F + o] + bu, 0.f);
    }
}

// ---------------------------------------------------------------------------
extern "C" void kernel_launch(void* const* d_in, const int* in_sizes, int n_in,
                              void* d_out, int out_size, void* d_ws, size_t ws_size,
                              hipStream_t stream)
{
    const float* x    = (const float*)d_in[0];
    const float* adj  = (const float*)d_in[1];
    const float* Wmsg = (const float*)d_in[2];
    const float* bmsg = (const float*)d_in[3];
    const float* Wupd = (const float*)d_in[4];
    const float* bupd = (const float*)d_in[5];
    float* out = (float*)d_out;

    const size_t rows = (size_t)B_ * N_;                 // 2048
    int*    c1   = (int*)d_ws;                           // 4 counters (64B reserved)
    float*  xi   = (float*)((char*)d_ws + 64);           // 1 MB
    float*  xu   = xi + rows * F;                        // 1 MB
    int*    lstG = (int*)(xu + rows * F);                // rows*LSTW ints
    int*    cntG = lstG + rows * LSTW;                   // rows ints
    __half* xjH  = (__half*)(cntG + rows);               // (rows+4)*F halfs

    hipMemsetAsync(c1, 0, 16, stream);
    k_all<<<dim3(512), dim3(512), 0, stream>>>(
        x, adj, Wmsg, bmsg, Wupd, bupd, xi, xjH, xu, lstG, cntG, c1, out);
}

// Round 8
// 95.180 us; speedup vs baseline: 1.0328x; 1.0328x over previous
//
#include <hip/hip_runtime.h>
#include <hip/hip_fp16.h>

// Problem constants (reference: B=4, N=512, F_IN=F_OUT=128)
constexpr int B_   = 4;
constexpr int N_   = 512;
constexpr int F    = 128;
constexpr int RB   = 4;     // rows per block (both kernels)
constexpr int LSTW = 520;   // neighbor-list stride (512 + pad)

// ---------------------------------------------------------------------------
// Kernel 1 (512 blocks x 256 threads): per 4 node rows
//   - wave w ballot-compacts adj row w straight to lstG/cntG (sentinel pads)
//   - GEMM, full K=128 per thread (no K-split, no LDS combine):
//       g = t>>7:  g0 -> xi rows 0-3 (+b_msg) and xu rows 0-1
//                  g1 -> xj rows 0-3 (fp16)   and xu rows 2-3
//   - LDS: 2 KB x-tile only; one barrier
// ---------------------------------------------------------------------------
__global__ __launch_bounds__(256) void k_pre(
    const float* __restrict__ x,
    const float* __restrict__ adj,
    const float* __restrict__ Wmsg,
    const float* __restrict__ bmsg,
    const float* __restrict__ Wupd,
    float*  __restrict__ xi,
    __half* __restrict__ xjH,
    float*  __restrict__ xu,
    int*    __restrict__ lstG,
    int*    __restrict__ cntG)
{
    __shared__ __align__(16) float xs[RB][F];   // 2 KB

    const int t    = threadIdx.x;
    const int lane = t & 63;
    const int w    = t >> 6;             // wave 0..3 (owns row w for compaction)
    const int g    = t >> 7;             // 0: xi+xu01, 1: xj+xu23
    const int o    = t & 127;            // output column
    const int r0   = blockIdx.x * RB;
    const int b    = r0 >> 9;
    const int PADJ = B_ * N_ - b * N_;   // shared sentinel row (global row 2048)

    // sentinel xj row: relu(xi - 60000) == 0
    if (blockIdx.x == 0 && t < F)
        xjH[(size_t)(B_ * N_) * F + t] = __float2half(-60000.f);

    // x rows -> LDS
    for (int ix = t; ix < RB * F; ix += 256)
        xs[ix >> 7][ix & 127] = x[(size_t)r0 * F + ix];

    // ---- ballot compaction: wave w owns row r0+w, list straight to global
    {
        const float* arow = adj + (size_t)(r0 + w) * N_;
        int* lrow = lstG + (size_t)(r0 + w) * LSTW;
        int base = 0;
        #pragma unroll
        for (int s = 0; s < 8; ++s) {
            const float a = arow[s * 64 + lane];
            const unsigned long long m = __ballot(a != 0.f);
            const int off = __popcll(m & ((1ull << lane) - 1ull));
            if (a != 0.f) lrow[base + off] = s * 64 + lane;
            base += __popcll(m);
        }
        const int np = (base + 7) & ~7;
        if (lane < np - base) lrow[base + lane] = PADJ;   // sentinel pads
        if (lane == 0) cntG[r0 + w] = np;
    }
    __syncthreads();

    // ---- GEMM: full K=128 per thread, 6 accumulators
    //   acc[0..3]: (g0: xi, g1: xj) rows 0..3, weight WA
    //   acc[4..5]: xu rows 2g, 2g+1, weight Wupd
    const float* WA = Wmsg + (size_t)g * F * F;   // g0: Wi, g1: Wj
    float acc0 = 0.f, acc1 = 0.f, acc2 = 0.f, acc3 = 0.f, acc4 = 0.f, acc5 = 0.f;
    const int ru = 2 * g;

    #pragma unroll
    for (int k = 0; k < F; k += 4) {
        const float4 x0 = *reinterpret_cast<const float4*>(&xs[0][k]);
        const float4 x1 = *reinterpret_cast<const float4*>(&xs[1][k]);
        const float4 x2 = *reinterpret_cast<const float4*>(&xs[2][k]);
        const float4 x3 = *reinterpret_cast<const float4*>(&xs[3][k]);
        #pragma unroll
        for (int u = 0; u < 4; ++u) {
            const float wa = WA[(size_t)(k + u) * F + o];
            const float wu = Wupd[(size_t)(k + u) * F + o];
            const float e0 = reinterpret_cast<const float*>(&x0)[u];
            const float e1 = reinterpret_cast<const float*>(&x1)[u];
            const float e2 = reinterpret_cast<const float*>(&x2)[u];
            const float e3 = reinterpret_cast<const float*>(&x3)[u];
            acc0 = fmaf(e0, wa, acc0);
            acc1 = fmaf(e1, wa, acc1);
            acc2 = fmaf(e2, wa, acc2);
            acc3 = fmaf(e3, wa, acc3);
            const float eu0 = (g == 0) ? e0 : e2;
            const float eu1 = (g == 0) ? e1 : e3;
            acc4 = fmaf(eu0, wu, acc4);
            acc5 = fmaf(eu1, wu, acc5);
        }
    }

    if (g == 0) {
        const float bm = bmsg[o];
        xi[(size_t)(r0 + 0) * F + o] = acc0 + bm;
        xi[(size_t)(r0 + 1) * F + o] = acc1 + bm;
        xi[(size_t)(r0 + 2) * F + o] = acc2 + bm;
        xi[(size_t)(r0 + 3) * F + o] = acc3 + bm;
    } else {
        xjH[(size_t)(r0 + 0) * F + o] = __float2half(acc0);
        xjH[(size_t)(r0 + 1) * F + o] = __float2half(acc1);
        xjH[(size_t)(r0 + 2) * F + o] = __float2half(acc2);
        xjH[(size_t)(r0 + 3) * F + o] = __float2half(acc3);
    }
    xu[(size_t)(r0 + ru + 0) * F + o] = acc4;
    xu[(size_t)(r0 + ru + 1) * F + o] = acc5;
}

// ---------------------------------------------------------------------------
// Kernel 2 (512 blocks x 256 threads): per 4 node rows
//   - wave w gathers row r0+w over fp16 xj (8-deep unroll, index prefetch,
//     sentinel pads contribute exactly 0)
//   - update GEMM: thread (o,g) -> rows 2g,2g+1, full K=128
//   - out = relu(xu + agg@Wupd[F:2F] + b_upd)
// ---------------------------------------------------------------------------
__global__ __launch_bounds__(256) void k_agg(
    const int*    __restrict__ lstG,
    const int*    __restrict__ cntG,
    const float*  __restrict__ xi,
    const __half* __restrict__ xjH,
    const float*  __restrict__ xu,
    const float*  __restrict__ Wupd,
    const float*  __restrict__ bupd,
    float* __restrict__ out)
{
    __shared__ __align__(16) float agg[RB][F];   // 2 KB

    const int t    = threadIdx.x;
    const int lane = t & 63;
    const int w    = t >> 6;            // wave 0..3 -> row w
    const int o    = t & 127;
    const int g    = t >> 7;            // 0: rows 0-1, 1: rows 2-3
    const int r0   = blockIdx.x * RB;
    const int b    = r0 >> 9;

    // ---- gather: wave w owns row r0+w
    {
        const __half* xjb = xjH + (size_t)b * N_ * F;
        const float2 xir2 = *reinterpret_cast<const float2*>(
            &xi[(size_t)(r0 + w) * F + 2 * lane]);
        const int np = cntG[r0 + w];
        const int* lrow = lstG + (size_t)(r0 + w) * LSTW;
        float2 acc = {0.f, 0.f};

        if (np > 0) {
            int4 a = *reinterpret_cast<const int4*>(&lrow[0]);
            int4 c = *reinterpret_cast<const int4*>(&lrow[4]);
            for (int k = 0; k < np; k += 8) {
                const int4 an = *reinterpret_cast<const int4*>(&lrow[k + 8]);
                const int4 cn = *reinterpret_cast<const int4*>(&lrow[k + 12]);
                const float2 v0 = __half22float2(*reinterpret_cast<const __half2*>(&xjb[(size_t)a.x * F + 2 * lane]));
                const float2 v1 = __half22float2(*reinterpret_cast<const __half2*>(&xjb[(size_t)a.y * F + 2 * lane]));
                const float2 v2 = __half22float2(*reinterpret_cast<const __half2*>(&xjb[(size_t)a.z * F + 2 * lane]));
                const float2 v3 = __half22float2(*reinterpret_cast<const __half2*>(&xjb[(size_t)a.w * F + 2 * lane]));
                const float2 v4 = __half22float2(*reinterpret_cast<const __half2*>(&xjb[(size_t)c.x * F + 2 * lane]));
                const float2 v5 = __half22float2(*reinterpret_cast<const __half2*>(&xjb[(size_t)c.y * F + 2 * lane]));
                const float2 v6 = __half22float2(*reinterpret_cast<const __half2*>(&xjb[(size_t)c.z * F + 2 * lane]));
                const float2 v7 = __half22float2(*reinterpret_cast<const __half2*>(&xjb[(size_t)c.w * F + 2 * lane]));
                acc.x += fmaxf(xir2.x + v0.x, 0.f);  acc.y += fmaxf(xir2.y + v0.y, 0.f);
                acc.x += fmaxf(xir2.x + v1.x, 0.f);  acc.y += fmaxf(xir2.y + v1.y, 0.f);
                acc.x += fmaxf(xir2.x + v2.x, 0.f);  acc.y += fmaxf(xir2.y + v2.y, 0.f);
                acc.x += fmaxf(xir2.x + v3.x, 0.f);  acc.y += fmaxf(xir2.y + v3.y, 0.f);
                acc.x += fmaxf(xir2.x + v4.x, 0.f);  acc.y += fmaxf(xir2.y + v4.y, 0.f);
                acc.x += fmaxf(xir2.x + v5.x, 0.f);  acc.y += fmaxf(xir2.y + v5.y, 0.f);
                acc.x += fmaxf(xir2.x + v6.x, 0.f);  acc.y += fmaxf(xir2.y + v6.y, 0.f);
                acc.x += fmaxf(xir2.x + v7.x, 0.f);  acc.y += fmaxf(xir2.y + v7.y, 0.f);
                a = an; c = cn;
            }
        }
        *reinterpret_cast<float2*>(&agg[w][2 * lane]) = acc;
    }
    __syncthreads();

    // ---- update GEMM: rows 2g, 2g+1, full K=128 (agg reads broadcast)
    float res0 = 0.f, res1 = 0.f;
    const int rA = 2 * g, rB2 = 2 * g + 1;
    #pragma unroll
    for (int k = 0; k < F; k += 4) {
        const float4 a0 = *reinterpret_cast<const float4*>(&agg[rA][k]);
        const float4 a1 = *reinterpret_cast<const float4*>(&agg[rB2][k]);
        #pragma unroll
        for (int u = 0; u < 4; ++u) {
            const float wv = Wupd[(size_t)(F + k + u) * F + o];
            res0 = fmaf(reinterpret_cast<const float*>(&a0)[u], wv, res0);
            res1 = fmaf(reinterpret_cast<const float*>(&a1)[u], wv, res1);
        }
    }
    const float bu = bupd[o];
    out[(size_t)(r0 + rA) * F + o] =
        fmaxf(res0 + xu[(size_t)(r0 + rA) * F + o] + bu, 0.f);
    out[(size_t)(r0 + rB2) * F + o] =
        fmaxf(res1 + xu[(size_t)(r0 + rB2) * F + o] + bu, 0.f);
}

// ---------------------------------------------------------------------------
extern "C" void kernel_launch(void* const* d_in, const int* in_sizes, int n_in,
                              void* d_out, int out_size, void* d_ws, size_t ws_size,
                              hipStream_t stream)
{
    const float* x    = (const float*)d_in[0];
    const float* adj  = (const float*)d_in[1];
    const float* Wmsg = (const float*)d_in[2];
    const float* bmsg = (const float*)d_in[3];
    const float* Wupd = (const float*)d_in[4];
    const float* bupd = (const float*)d_in[5];
    float* out = (float*)d_out;

    const size_t rows = (size_t)B_ * N_;               // 2048
    float*  xi   = (float*)d_ws;                       // 1 MB
    float*  xu   = xi + rows * F;                      // 1 MB
    int*    lstG = (int*)(xu + rows * F);              // rows*LSTW ints
    int*    cntG = lstG + rows * LSTW;                 // rows ints
    __half* xjH  = (__half*)(cntG + rows);             // (rows+1)*F halfs

    k_pre<<<dim3(rows / RB), dim3(256), 0, stream>>>(
        x, adj, Wmsg, bmsg, Wupd, xi, xjH, xu, lstG, cntG);
    k_agg<<<dim3(rows / RB), dim3(256), 0, stream>>>(
        lstG, cntG, xi, xjH, xu, Wupd, bupd, out);
}

// Round 9
// 27.226 us; speedup vs baseline: 3.6106x; 3.4958x over previous
//
#include <hip/hip_runtime.h>

// Problem constants (reference: B=4, N=512, F_IN=F_OUT=128)
constexpr int B_   = 4;
constexpr int N_   = 512;
constexpr int F    = 128;
constexpr int RB   = 8;     // rows per block
constexpr int LSTW = 528;   // neighbor-list stride (512 + 16, 16-mult)

typedef short bf16x8 __attribute__((ext_vector_type(8)));   // 8 bf16 = 4 VGPR
typedef float f32x4  __attribute__((ext_vector_type(4)));

__device__ inline ushort f2bf(float f) {      // RNE f32 -> bf16 bits
    union { float f; uint u; } v; v.f = f;
    const uint b = v.u + (0x7FFFu + ((v.u >> 16) & 1u));
    return (ushort)(b >> 16);
}

// ---------------------------------------------------------------------------
// SINGLE kernel, 256 blocks x 512 threads (1 block/CU), no cross-block deps.
// Block owns 8 node rows. Each wave w owns row r0+w.
//
//  A. stage x rows (f32 LDS) + Wj^T (bf16 LDS); ballot-compact adj row w
//     into lstG (global scratch, wave-local round-trip; pad idx 0)
//  B. B-fragments (Wj) -> 128 VGPRs; xi/xu via in-wave k-split scalar GEMM
//     (o = w*16 + (lane&15), k-quarter = lane>>4, shfl_xor reduce -> no
//     redundant W reads, no LDS partials); xi -> LDS (f32, + b_msg)
//  C. per-wave MFMA recompute loop over its neighbor list, chunks of 16:
//     stage 16 x[j] rows bf16 -> wave-private LDS region (unioned with Wj^T),
//     8 Ntiles x 4 Ksteps mfma_16x16x32_bf16 -> xj chunk in regs,
//     epilogue: agg[w][col] += sum_m relu(xi[w][col] + xj[m][col])
//     (predicated mi<np, shfl_xor(16/32) cross-lane sum, lanes<16 RMW)
//  D. update GEMM (same in-wave k-split): out = relu(xu + agg@W2 + b_upd)
// ---------------------------------------------------------------------------
__global__ __launch_bounds__(512, 2) void k_one(
    const float* __restrict__ x,
    const float* __restrict__ adj,
    const float* __restrict__ Wmsg,
    const float* __restrict__ bmsg,
    const float* __restrict__ Wupd,
    const float* __restrict__ bupd,
    int*   __restrict__ lstG,
    float* __restrict__ out)
{
    __shared__ union {
        __align__(16) ushort bt[F][136];        // Wj^T bf16 (34.8 KB)
        __align__(16) ushort ax[8][16][136];    // per-wave A-chunks (34.8 KB)
    } u;
    __shared__ float xs [RB][F];                // x rows f32   (4 KB)
    __shared__ float xiL[RB][F];                // xi rows f32  (4 KB)
    __shared__ float agg[RB][F];                // aggregate    (4 KB)

    const int t    = threadIdx.x;
    const int lane = t & 63;
    const int w    = t >> 6;             // wave 0..7 -> owns row r0+w
    const int kg   = lane >> 4;          // k-group / MFMA k-subgroup (0..3)
    const int c16  = lane & 15;          // MFMA row/col within tile
    const int r0   = blockIdx.x * RB;
    const int b    = r0 >> 9;
    const int oS   = w * 16 + c16;       // this thread's output column (0..127)

    // zero agg (1024 floats)
    reinterpret_cast<float*>(agg)[t]       = 0.f;
    reinterpret_cast<float*>(agg)[t + 512] = 0.f;

    // stage x rows -> xs
    for (int v = t; v < RB * F; v += 512)
        xs[v >> 7][v & 127] = x[(size_t)r0 * F + v];

    // stage Wj^T -> bt (coalesced read, bf16 convert, transposed write)
    {
        const float* Wj = Wmsg + (size_t)F * F;
        for (int v = t; v < F * F; v += 512) {
            const int k = v >> 7, o = v & 127;
            u.bt[o][k] = f2bf(Wj[v]);
        }
    }

    // ballot-compact adj row w -> lstG (ascending j, pad to 16-mult with 0)
    int np;
    {
        const float* arow = adj + (size_t)(r0 + w) * N_;
        int* lrow = lstG + (size_t)(r0 + w) * LSTW;
        int base = 0;
        #pragma unroll
        for (int s = 0; s < 8; ++s) {
            const float a = arow[s * 64 + lane];
            const unsigned long long m = __ballot(a != 0.f);
            const int off = __popcll(m & ((1ull << lane) - 1ull));
            if (a != 0.f) lrow[base + off] = s * 64 + lane;
            base += __popcll(m);
        }
        const int np16 = (base + 15) & ~15;
        if (lane < np16 - base) lrow[base + lane] = 0;   // pad (predicated off)
        np = base;                                        // wave-uniform
    }
    __syncthreads();    // (1) xs, bt staged

    // ---- B-fragments (Wj) -> registers: 8 Ntiles x 4 Ksteps
    bf16x8 bf[8][4];
    #pragma unroll
    for (int nt = 0; nt < 8; ++nt)
        #pragma unroll
        for (int ks = 0; ks < 4; ++ks)
            bf[nt][ks] = *reinterpret_cast<const bf16x8*>(
                &u.bt[nt * 16 + c16][ks * 32 + kg * 8]);

    // ---- xi / xu scalar GEMM, in-wave k-split (k in [kg*32, kg*32+32))
    float xiA[RB] = {0,0,0,0,0,0,0,0};
    float xuA[RB] = {0,0,0,0,0,0,0,0};
    #pragma unroll
    for (int k0 = 0; k0 < 32; k0 += 4) {
        const int k = kg * 32 + k0;
        float4 xv[RB];
        #pragma unroll
        for (int r = 0; r < RB; ++r)
            xv[r] = *reinterpret_cast<const float4*>(&xs[r][k]);
        #pragma unroll
        for (int uu = 0; uu < 4; ++uu) {
            const float wi = Wmsg[(size_t)(k + uu) * F + oS];
            const float wu = Wupd[(size_t)(k + uu) * F + oS];
            #pragma unroll
            for (int r = 0; r < RB; ++r) {
                const float xk = reinterpret_cast<const float*>(&xv[r])[uu];
                xiA[r] = fmaf(xk, wi, xiA[r]);
                xuA[r] = fmaf(xk, wu, xuA[r]);
            }
        }
    }
    #pragma unroll
    for (int r = 0; r < RB; ++r) {       // reduce over the 4 k-groups
        xiA[r] += __shfl_xor(xiA[r], 16);  xiA[r] += __shfl_xor(xiA[r], 32);
        xuA[r] += __shfl_xor(xuA[r], 16);  xuA[r] += __shfl_xor(xuA[r], 32);
    }
    if (kg == 0) {
        const float bm = bmsg[oS];
        #pragma unroll
        for (int r = 0; r < RB; ++r) xiL[r][oS] = xiA[r] + bm;
    }
    __syncthreads();    // (2) xi ready; bt consumed -> ax may overwrite

    // ---- per-wave MFMA recompute + aggregate (no barriers inside)
    {
        const int* lrow = lstG + (size_t)(r0 + w) * LSTW;
        const int nch = (np + 15) >> 4;
        for (int c = 0; c < nch; ++c) {
            // stage 16 neighbor x rows -> wave-private bf16 LDS region
            const int m    = lane >> 2;          // row within chunk (0..15)
            const int sseg = lane & 3;           // 32-col segment
            const int jdx  = lrow[c * 16 + m];
            const float* xrow = x + ((size_t)(b * N_) + jdx) * F;
            #pragma unroll
            for (int i = 0; i < 8; ++i) {
                const int q = sseg * 8 + i;      // float4 index 0..31
                const float4 p = *reinterpret_cast<const float4*>(&xrow[4 * q]);
                uint2 pk;
                pk.x = (uint)f2bf(p.x) | ((uint)f2bf(p.y) << 16);
                pk.y = (uint)f2bf(p.z) | ((uint)f2bf(p.w) << 16);
                *reinterpret_cast<uint2*>(&u.ax[w][m][4 * q]) = pk;
            }
            // A-fragments for this chunk (wave-local LDS RAW; compiler waits)
            bf16x8 af[4];
            #pragma unroll
            for (int ks = 0; ks < 4; ++ks)
                af[ks] = *reinterpret_cast<const bf16x8*>(
                    &u.ax[w][c16][ks * 32 + kg * 8]);
            // 8 Ntiles x (4 chained MFMA) + epilogue
            #pragma unroll
            for (int nt = 0; nt < 8; ++nt) {
                f32x4 acc = {0.f, 0.f, 0.f, 0.f};
                #pragma unroll
                for (int ks = 0; ks < 4; ++ks)
                    acc = __builtin_amdgcn_mfma_f32_16x16x32_bf16(
                        af[ks], bf[nt][ks], acc, 0, 0, 0);
                const float xiv = xiL[w][nt * 16 + c16];
                float s = 0.f;
                #pragma unroll
                for (int g = 0; g < 4; ++g) {
                    const int mi = c * 16 + kg * 4 + g;   // D row = (lane>>4)*4+g
                    const float vv = fmaxf(xiv + acc[g], 0.f);
                    s += (mi < np) ? vv : 0.f;
                }
                s += __shfl_xor(s, 16);
                s += __shfl_xor(s, 32);
                if (lane < 16) agg[w][nt * 16 + lane] += s;
            }
        }
    }
    __syncthreads();    // (3) agg complete

    // ---- update GEMM, in-wave k-split: out = relu(xu + agg@W2 + b_upd)
    {
        const float* W2 = Wupd + (size_t)F * F;
        float so[RB] = {0,0,0,0,0,0,0,0};
        #pragma unroll
        for (int k0 = 0; k0 < 32; k0 += 4) {
            const int k = kg * 32 + k0;
            float4 av[RB];
            #pragma unroll
            for (int r = 0; r < RB; ++r)
                av[r] = *reinterpret_cast<const float4*>(&agg[r][k]);
            #pragma unroll
            for (int uu = 0; uu < 4; ++uu) {
                const float wv = W2[(size_t)(k + uu) * F + oS];
                #pragma unroll
                for (int r = 0; r < RB; ++r)
                    so[r] = fmaf(reinterpret_cast<const float*>(&av[r])[uu], wv, so[r]);
            }
        }
        #pragma unroll
        for (int r = 0; r < RB; ++r) {
            so[r] += __shfl_xor(so[r], 16);
            so[r] += __shfl_xor(so[r], 32);
        }
        if (kg == 0) {
            const float bu = bupd[oS];
            #pragma unroll
            for (int r = 0; r < RB; ++r)
                out[(size_t)(r0 + r) * F + oS] = fmaxf(so[r] + xuA[r] + bu, 0.f);
        }
    }
}

// ---------------------------------------------------------------------------
extern "C" void kernel_launch(void* const* d_in, const int* in_sizes, int n_in,
                              void* d_out, int out_size, void* d_ws, size_t ws_size,
                              hipStream_t stream)
{
    const float* x    = (const float*)d_in[0];
    const float* adj  = (const float*)d_in[1];
    const float* Wmsg = (const float*)d_in[2];
    const float* bmsg = (const float*)d_in[3];
    const float* Wupd = (const float*)d_in[4];
    const float* bupd = (const float*)d_in[5];
    float* out = (float*)d_out;
    int*   lstG = (int*)d_ws;   // 2048 * 528 ints = 4.3 MB

    k_one<<<dim3((B_ * N_) / RB), dim3(512), 0, stream>>>(
        x, adj, Wmsg, bmsg, Wupd, bupd, lstG, out);
}

// Round 10
// 25.906 us; speedup vs baseline: 3.7945x; 1.0510x over previous
//
#include <hip/hip_runtime.h>
#include <hip/hip_fp16.h>

// Problem constants (reference: B=4, N=512, F_IN=F_OUT=128)
constexpr int B_   = 4;
constexpr int N_   = 512;
constexpr int F    = 128;
constexpr int R2B  = 8;     // rows per block, kernel 2
constexpr int LSTW = 520;   // neighbor-list stride (512 + pad)

// ---------------------------------------------------------------------------
// Kernel 1 (768 blocks x 256 threads): tiled GEMM  BM=16 x BN=64
//   grid = 128 row-chunks x 6 col-tiles; col-tile -> (matrix, half):
//     m6 0,1: xi = x@Wi + b_msg  (cols 0-63 / 64-127)
//     m6 2,3: xj = x@Wj  -> fp16
//     m6 4,5: xu = x@Wupd[0:F]
//   W traffic: 768 x 32KB = 24 MB (vs 98 MB at BM=4). 3 blocks/CU.
//   m6==0 blocks also ballot-compact their 16 adj rows -> lstG/cntG.
// ---------------------------------------------------------------------------
__global__ __launch_bounds__(256) void k_mm(
    const float* __restrict__ x,
    const float* __restrict__ adj,
    const float* __restrict__ Wmsg,
    const float* __restrict__ bmsg,
    const float* __restrict__ Wupd,
    float*  __restrict__ xi,
    __half* __restrict__ xjH,
    float*  __restrict__ xu,
    int*    __restrict__ lstG,
    int*    __restrict__ cntG)
{
    __shared__ __align__(16) float xs[16][F];   // 8 KB

    const int t    = threadIdx.x;
    const int lane = t & 63;
    const int w    = t >> 6;              // wave 0..3 -> rows w*4..w*4+3
    const int rc   = blockIdx.x / 6;      // row-chunk
    const int m6   = blockIdx.x % 6;      // (matrix, col-half)
    const int r0   = rc * 16;
    const int mat  = m6 >> 1;             // 0: xi, 1: xj, 2: xu
    const int col  = (m6 & 1) * 64 + lane;

    // sentinel xj row (one block): relu(xi - 60000) == 0
    if (blockIdx.x == 0 && t < F)
        xjH[(size_t)(B_ * N_) * F + t] = __float2half(-60000.f);

    // ---- stage x tile (16 rows x 128), coalesced float4
    {
        const float4* src = reinterpret_cast<const float4*>(x + (size_t)r0 * F);
        float4* dst = reinterpret_cast<float4*>(&xs[0][0]);
        dst[t]       = src[t];
        dst[t + 256] = src[t + 256];
    }

    // ---- compaction (m6==0 blocks): wave w does rows w*4..w*4+3
    if (m6 == 0) {
        const int b    = r0 >> 9;
        const int PADJ = B_ * N_ - b * N_;         // per-batch sentinel index
        #pragma unroll
        for (int rr = 0; rr < 4; ++rr) {
            const int grow = r0 + w * 4 + rr;
            const float* arow = adj + (size_t)grow * N_;
            int* lrow = lstG + (size_t)grow * LSTW;
            int base = 0;
            #pragma unroll
            for (int s = 0; s < 8; ++s) {
                const float a = arow[s * 64 + lane];
                const unsigned long long m = __ballot(a != 0.f);
                const int off = __popcll(m & ((1ull << lane) - 1ull));
                if (a != 0.f) lrow[base + off] = s * 64 + lane;
                base += __popcll(m);
            }
            const int np = (base + 7) & ~7;
            if (lane < np - base) lrow[base + lane] = PADJ;   // sentinel pads
            if (lane == 0) cntG[grow] = np;
        }
    }
    __syncthreads();

    // ---- GEMM: 4 rows x 1 col per thread, K=128
    const float* W = (mat == 0) ? Wmsg
                   : (mat == 1) ? (Wmsg + (size_t)F * F)
                   : Wupd;
    const int w4 = w * 4;
    float acc0 = 0.f, acc1 = 0.f, acc2 = 0.f, acc3 = 0.f;

    #pragma unroll
    for (int k0 = 0; k0 < F; k0 += 4) {
        const float4 x0 = *reinterpret_cast<const float4*>(&xs[w4 + 0][k0]);
        const float4 x1 = *reinterpret_cast<const float4*>(&xs[w4 + 1][k0]);
        const float4 x2 = *reinterpret_cast<const float4*>(&xs[w4 + 2][k0]);
        const float4 x3 = *reinterpret_cast<const float4*>(&xs[w4 + 3][k0]);
        #pragma unroll
        for (int u = 0; u < 4; ++u) {
            const float wv = W[(size_t)(k0 + u) * F + col];
            acc0 = fmaf(reinterpret_cast<const float*>(&x0)[u], wv, acc0);
            acc1 = fmaf(reinterpret_cast<const float*>(&x1)[u], wv, acc1);
            acc2 = fmaf(reinterpret_cast<const float*>(&x2)[u], wv, acc2);
            acc3 = fmaf(reinterpret_cast<const float*>(&x3)[u], wv, acc3);
        }
    }

    // ---- epilogue (coalesced 256B stores per wave)
    if (mat == 0) {
        const float bm = bmsg[col];
        xi[(size_t)(r0 + w4 + 0) * F + col] = acc0 + bm;
        xi[(size_t)(r0 + w4 + 1) * F + col] = acc1 + bm;
        xi[(size_t)(r0 + w4 + 2) * F + col] = acc2 + bm;
        xi[(size_t)(r0 + w4 + 3) * F + col] = acc3 + bm;
    } else if (mat == 1) {
        xjH[(size_t)(r0 + w4 + 0) * F + col] = __float2half(acc0);
        xjH[(size_t)(r0 + w4 + 1) * F + col] = __float2half(acc1);
        xjH[(size_t)(r0 + w4 + 2) * F + col] = __float2half(acc2);
        xjH[(size_t)(r0 + w4 + 3) * F + col] = __float2half(acc3);
    } else {
        xu[(size_t)(r0 + w4 + 0) * F + col] = acc0;
        xu[(size_t)(r0 + w4 + 1) * F + col] = acc1;
        xu[(size_t)(r0 + w4 + 2) * F + col] = acc2;
        xu[(size_t)(r0 + w4 + 3) * F + col] = acc3;
    }
}

// ---------------------------------------------------------------------------
// Kernel 2 (256 blocks x 512 threads): byte-identical to R5's k_agg
// ---------------------------------------------------------------------------
__global__ __launch_bounds__(512) void k_agg(
    const int*    __restrict__ lstG,
    const int*    __restrict__ cntG,
    const float*  __restrict__ xi,
    const __half* __restrict__ xjH,
    const float*  __restrict__ xu,
    const float*  __restrict__ Wupd,
    const float*  __restrict__ bupd,
    float* __restrict__ out)
{
    __shared__ __align__(16) float agg[R2B][F];

    const int t    = threadIdx.x;
    const int lane = t & 63;
    const int w    = t >> 6;            // wave 0..7 -> row w
    const int o    = t & 127;
    const int gg   = t >> 7;            // 0..3 -> rows 2gg, 2gg+1
    const int r0   = blockIdx.x * R2B;
    const int b    = r0 >> 9;

    // ---- gather: wave w owns row r0+w
    {
        const __half* xjb = xjH + (size_t)b * N_ * F;
        const float2 xir2 = *reinterpret_cast<const float2*>(
            &xi[(size_t)(r0 + w) * F + 2 * lane]);
        const int np = cntG[r0 + w];
        const int* lrow = lstG + (size_t)(r0 + w) * LSTW;
        float2 acc = {0.f, 0.f};

        if (np > 0) {
            int4 a = *reinterpret_cast<const int4*>(&lrow[0]);
            int4 c = *reinterpret_cast<const int4*>(&lrow[4]);
            for (int k = 0; k < np; k += 8) {
                const int4 an = *reinterpret_cast<const int4*>(&lrow[k + 8]);
                const int4 cn = *reinterpret_cast<const int4*>(&lrow[k + 12]);
                const float2 v0 = __half22float2(*reinterpret_cast<const __half2*>(&xjb[(size_t)a.x * F + 2 * lane]));
                const float2 v1 = __half22float2(*reinterpret_cast<const __half2*>(&xjb[(size_t)a.y * F + 2 * lane]));
                const float2 v2 = __half22float2(*reinterpret_cast<const __half2*>(&xjb[(size_t)a.z * F + 2 * lane]));
                const float2 v3 = __half22float2(*reinterpret_cast<const __half2*>(&xjb[(size_t)a.w * F + 2 * lane]));
                const float2 v4 = __half22float2(*reinterpret_cast<const __half2*>(&xjb[(size_t)c.x * F + 2 * lane]));
                const float2 v5 = __half22float2(*reinterpret_cast<const __half2*>(&xjb[(size_t)c.y * F + 2 * lane]));
                const float2 v6 = __half22float2(*reinterpret_cast<const __half2*>(&xjb[(size_t)c.z * F + 2 * lane]));
                const float2 v7 = __half22float2(*reinterpret_cast<const __half2*>(&xjb[(size_t)c.w * F + 2 * lane]));
                acc.x += fmaxf(xir2.x + v0.x, 0.f);  acc.y += fmaxf(xir2.y + v0.y, 0.f);
                acc.x += fmaxf(xir2.x + v1.x, 0.f);  acc.y += fmaxf(xir2.y + v1.y, 0.f);
                acc.x += fmaxf(xir2.x + v2.x, 0.f);  acc.y += fmaxf(xir2.y + v2.y, 0.f);
                acc.x += fmaxf(xir2.x + v3.x, 0.f);  acc.y += fmaxf(xir2.y + v3.y, 0.f);
                acc.x += fmaxf(xir2.x + v4.x, 0.f);  acc.y += fmaxf(xir2.y + v4.y, 0.f);
                acc.x += fmaxf(xir2.x + v5.x, 0.f);  acc.y += fmaxf(xir2.y + v5.y, 0.f);
                acc.x += fmaxf(xir2.x + v6.x, 0.f);  acc.y += fmaxf(xir2.y + v6.y, 0.f);
                acc.x += fmaxf(xir2.x + v7.x, 0.f);  acc.y += fmaxf(xir2.y + v7.y, 0.f);
                a = an; c = cn;
            }
        }
        *reinterpret_cast<float2*>(&agg[w][2 * lane]) = acc;
    }
    __syncthreads();

    // ---- update GEMM: rows 2gg, 2gg+1, full K=128
    float res0 = 0.f, res1 = 0.f;
    const int rA = 2 * gg, rB2 = 2 * gg + 1;
    #pragma unroll
    for (int k = 0; k < F; k += 4) {
        const float4 a0 = *reinterpret_cast<const float4*>(&agg[rA][k]);
        const float4 a1 = *reinterpret_cast<const float4*>(&agg[rB2][k]);
        #pragma unroll
        for (int u = 0; u < 4; ++u) {
            const float wv = Wupd[(size_t)(F + k + u) * F + o];
            res0 = fmaf(reinterpret_cast<const float*>(&a0)[u], wv, res0);
            res1 = fmaf(reinterpret_cast<const float*>(&a1)[u], wv, res1);
        }
    }
    const float bu = bupd[o];
    out[(size_t)(r0 + rA) * F + o] =
        fmaxf(res0 + xu[(size_t)(r0 + rA) * F + o] + bu, 0.f);
    out[(size_t)(r0 + rB2) * F + o] =
        fmaxf(res1 + xu[(size_t)(r0 + rB2) * F + o] + bu, 0.f);
}

// ---------------------------------------------------------------------------
extern "C" void kernel_launch(void* const* d_in, const int* in_sizes, int n_in,
                              void* d_out, int out_size, void* d_ws, size_t ws_size,
                              hipStream_t stream)
{
    const float* x    = (const float*)d_in[0];
    const float* adj  = (const float*)d_in[1];
    const float* Wmsg = (const float*)d_in[2];
    const float* bmsg = (const float*)d_in[3];
    const float* Wupd = (const float*)d_in[4];
    const float* bupd = (const float*)d_in[5];
    float* out = (float*)d_out;

    const size_t rows = (size_t)B_ * N_;               // 2048
    float*  xi   = (float*)d_ws;                       // 1 MB
    float*  xu   = xi + rows * F;                      // 1 MB
    int*    lstG = (int*)(xu + rows * F);              // rows*LSTW ints
    int*    cntG = lstG + rows * LSTW;                 // rows ints
    __half* xjH  = (__half*)(cntG + rows);             // (rows+1)*F halfs

    k_mm<<<dim3(128 * 6), dim3(256), 0, stream>>>(
        x, adj, Wmsg, bmsg, Wupd, xi, xjH, xu, lstG, cntG);
    k_agg<<<dim3(rows / R2B), dim3(512), 0, stream>>>(
        lstG, cntG, xi, xjH, xu, Wupd, bupd, out);
}